// Round 1
// baseline (1211.776 us; speedup 1.0000x reference)
//
#include <hip/hip_runtime.h>
#include <cstdint>
#include <cstddef>

// Problem constants (fixed shapes from reference)
#define B_    8
#define C_    128
#define H_    256
#define W_    256
#define HWSZ  (256*256)
#define HS_   32
#define WS_   32
#define NTOK  1024          // tokens per batch (Hs*Ws)
#define PP_   64            // pixels per patch
#define EPS_  1e-6f
#define SCALE_QK 0.08838834764831845f   // 128^-0.5
#define SCALE_AT 0.25f                  // 16^-0.5

// bijective XCD swizzle: nwg divisible by 8; chunk = nwg/8
__device__ __forceinline__ int swz8(int wg, int chunk) {
  return (wg & 7) * chunk + (wg >> 3);
}

// ---------------------------------------------------------------------------
// K1: per-pixel LayerNorm stats (mu, rstd) + stoken = 8x8 block mean of LN(x)
// one block per patch; LDS pix layout [p][c] with c-block XOR swizzle
// ---------------------------------------------------------------------------
__global__ __launch_bounds__(256) void k1_ln_stoken(
    const float* __restrict__ x, const float* __restrict__ lnw, const float* __restrict__ lnb,
    float* __restrict__ stok, float* __restrict__ gmu, float* __restrict__ grs)
{
  __shared__ __align__(16) float sp[64*128];
  __shared__ float reds[4*64], redq[4*64];
  __shared__ float smu[64], srs[64];
  int wg = swz8(blockIdx.x, 1024);
  int b = wg >> 10, n = wg & 1023;
  int hs = n >> 5, ws = n & 31;
  int tid = threadIdx.x;

  int p = tid & 63;
  int pi = p >> 3, pj = p & 7;
  const float* xpix = x + (size_t)b*C_*HWSZ + (size_t)(hs*8 + pi)*W_ + (ws*8 + pj);
  #pragma unroll
  for (int it = 0; it < 8; ++it) {
    int cb = it*4 + (tid >> 6);       // c-block of 4
    int c0 = cb*4;
    float v0 = xpix[(size_t)(c0+0)*HWSZ];
    float v1 = xpix[(size_t)(c0+1)*HWSZ];
    float v2 = xpix[(size_t)(c0+2)*HWSZ];
    float v3 = xpix[(size_t)(c0+3)*HWSZ];
    float4 v; v.x=v0; v.y=v1; v.z=v2; v.w=v3;
    *(float4*)&sp[p*128 + 4*(cb ^ (p & 7))] = v;
  }
  __syncthreads();
  // per-pixel stats over C
  {
    int pp2 = tid & 63, cq = tid >> 6;
    float s = 0.f, q = 0.f;
    #pragma unroll
    for (int e = 0; e < 8; ++e) {
      int cb = cq*8 + e;
      float4 v = *(const float4*)&sp[pp2*128 + 4*(cb ^ (pp2 & 7))];
      s += v.x + v.y + v.z + v.w;
      q += v.x*v.x + v.y*v.y + v.z*v.z + v.w*v.w;
    }
    reds[cq*64 + pp2] = s; redq[cq*64 + pp2] = q;
  }
  __syncthreads();
  if (tid < 64) {
    float s = reds[tid] + reds[64+tid] + reds[128+tid] + reds[192+tid];
    float q = redq[tid] + redq[64+tid] + redq[128+tid] + redq[192+tid];
    float mu = s * (1.f/128.f);
    float var = q * (1.f/128.f) - mu*mu;
    float rs = rsqrtf(var + EPS_);
    smu[tid] = mu; srs[tid] = rs;
    size_t base = (size_t)wg*64 + tid;
    gmu[base] = mu; grs[base] = rs;
  }
  __syncthreads();
  // stoken: per-c mean over 64 pixels of normalized values
  {
    int c = tid >> 1, ph = tid & 1;
    float s = 0.f;
    #pragma unroll
    for (int q = 0; q < 32; ++q) {
      int pr = ph*32 + q;
      float v = sp[pr*128 + 4*((c >> 2) ^ (pr & 7)) + (c & 3)];
      s += (v - smu[pr]) * srs[pr];
    }
    s += __shfl_xor(s, 1);
    if (ph == 0)
      stok[(size_t)wg*128 + c] = lnw[c] * (s * (1.f/64.f)) + lnb[c];
  }
}

// ---------------------------------------------------------------------------
// K2: per-token: aff = softmax(pix @ st * scale), scatter-fold pix^T@aff -> sf0
//     (atomics), scatter-fold sum_p(aff) -> affsum, write aff
// ---------------------------------------------------------------------------
__global__ __launch_bounds__(256) void k2_aff(
    const float* __restrict__ x, const float* __restrict__ lnw, const float* __restrict__ lnb,
    const float* __restrict__ stok, const float* __restrict__ gmu, const float* __restrict__ grs,
    float* __restrict__ aff_g, float* __restrict__ affsum, float* __restrict__ sf0)
{
  __shared__ __align__(16) float sp[64*128];      // normalized pix [p][c swizzled]
  __shared__ __align__(16) float st_s[9*128];     // [k][c]
  __shared__ __align__(16) float aff_s[64*12];    // [p][k] padded to 12
  __shared__ float smu[64], srs[64], wl[128], bl[128];
  __shared__ float red[4*16*36];                  // phase2 cross-wave reduce
  int wg = swz8(blockIdx.x, 1024);
  int b = wg >> 10, n = wg & 1023, hs = n >> 5, ws = n & 31;
  int tid = threadIdx.x;

  // phase 0: small loads
  if (tid < 64) { smu[tid] = gmu[(size_t)wg*64 + tid]; srs[tid] = grs[(size_t)wg*64 + tid]; }
  else if (tid < 192) { int l = tid - 64; wl[l] = lnw[l]; bl[l] = lnb[l]; }
  for (int l = tid; l < 1152; l += 256) {
    int k = l >> 7, c = l & 127;
    int dh = k/3 - 1, dw = k - (k/3)*3 - 1;
    int hs2 = hs + dh, ws2 = ws + dw;
    float v = 0.f;
    if ((unsigned)hs2 < 32u && (unsigned)ws2 < 32u)
      v = stok[((size_t)b*NTOK + hs2*32 + ws2)*128 + c];
    st_s[l] = v;
  }
  __syncthreads();
  // phase 1: load x patch, normalize, store swizzled
  {
    int p = tid & 63;
    int pi = p >> 3, pj = p & 7;
    const float* xpix = x + (size_t)b*C_*HWSZ + (size_t)(hs*8 + pi)*W_ + (ws*8 + pj);
    float mu = smu[p], rs = srs[p];
    #pragma unroll
    for (int it = 0; it < 8; ++it) {
      int cb = it*4 + (tid >> 6);
      int c0 = cb*4;
      float v0 = xpix[(size_t)(c0+0)*HWSZ];
      float v1 = xpix[(size_t)(c0+1)*HWSZ];
      float v2 = xpix[(size_t)(c0+2)*HWSZ];
      float v3 = xpix[(size_t)(c0+3)*HWSZ];
      float4 y;
      y.x = wl[c0+0]*((v0-mu)*rs) + bl[c0+0];
      y.y = wl[c0+1]*((v1-mu)*rs) + bl[c0+1];
      y.z = wl[c0+2]*((v2-mu)*rs) + bl[c0+2];
      y.w = wl[c0+3]*((v3-mu)*rs) + bl[c0+3];
      *(float4*)&sp[p*128 + 4*(cb ^ (p & 7))] = y;
    }
  }
  __syncthreads();
  // phase 2: logits[p][k] = sum_c pix[p][c]*st[k][c]
  {
    int pg = tid & 15;      // p = 4*pg + r
    int cg = tid >> 4;      // c = 8*cg .. 8*cg+7
    float pr[4][8];
    #pragma unroll
    for (int r = 0; r < 4; ++r) {
      int p2 = 4*pg + r;
      #pragma unroll
      for (int hh = 0; hh < 2; ++hh) {
        int cb = 2*cg + hh;
        float4 v = *(const float4*)&sp[p2*128 + 4*(cb ^ (p2 & 7))];
        pr[r][hh*4+0]=v.x; pr[r][hh*4+1]=v.y; pr[r][hh*4+2]=v.z; pr[r][hh*4+3]=v.w;
      }
    }
    float acc[4][9];
    #pragma unroll
    for (int r = 0; r < 4; ++r)
      #pragma unroll
      for (int k = 0; k < 9; ++k) acc[r][k] = 0.f;
    #pragma unroll
    for (int k = 0; k < 9; ++k) {
      float4 s0 = *(const float4*)&st_s[k*128 + 8*cg];
      float4 s1 = *(const float4*)&st_s[k*128 + 8*cg + 4];
      #pragma unroll
      for (int r = 0; r < 4; ++r)
        acc[r][k] += pr[r][0]*s0.x + pr[r][1]*s0.y + pr[r][2]*s0.z + pr[r][3]*s0.w
                   + pr[r][4]*s1.x + pr[r][5]*s1.y + pr[r][6]*s1.z + pr[r][7]*s1.w;
    }
    #pragma unroll
    for (int r = 0; r < 4; ++r)
      #pragma unroll
      for (int k = 0; k < 9; ++k) {
        float v = acc[r][k];
        v += __shfl_xor(v, 16);
        v += __shfl_xor(v, 32);
        acc[r][k] = v;
      }
    if ((tid & 48) == 0) {
      int w = tid >> 6;
      #pragma unroll
      for (int r = 0; r < 4; ++r)
        #pragma unroll
        for (int k = 0; k < 9; ++k)
          red[(w*16 + pg)*36 + r*9 + k] = acc[r][k];
    }
  }
  __syncthreads();
  for (int l = tid; l < 576; l += 256) {
    float v = red[l] + red[576+l] + red[1152+l] + red[1728+l];
    int pg = l/36, rem = l - pg*36;
    int r = rem/9, k = rem - r*9;
    aff_s[(4*pg + r)*12 + k] = v * SCALE_QK;
  }
  __syncthreads();
  if (tid < 64) {  // softmax over 9
    float mx = -1e30f;
    #pragma unroll
    for (int k = 0; k < 9; ++k) mx = fmaxf(mx, aff_s[tid*12 + k]);
    float e[9]; float ssum = 0.f;
    #pragma unroll
    for (int k = 0; k < 9; ++k) { e[k] = __expf(aff_s[tid*12 + k] - mx); ssum += e[k]; }
    float inv = 1.f / ssum;
    #pragma unroll
    for (int k = 0; k < 9; ++k) aff_s[tid*12 + k] = e[k]*inv;
  }
  __syncthreads();
  // write aff + affsum scatter
  for (int l = tid; l < 576; l += 256) {
    int p2 = l/9, k = l - p2*9;
    aff_g[(size_t)wg*576 + l] = aff_s[p2*12 + k];
  }
  if (tid < 9) {
    int k = tid;
    float s = 0.f;
    for (int p2 = 0; p2 < 64; ++p2) s += aff_s[p2*12 + k];
    int dh = k/3 - 1, dw = k - (k/3)*3 - 1;
    int hs2 = hs + dh, ws2 = ws + dw;
    if ((unsigned)hs2 < 32u && (unsigned)ws2 < 32u)
      atomicAdd(&affsum[(size_t)b*NTOK + hs2*32 + ws2], s);
  }
  // phase 3: sfpre[c][k] = sum_p pix[p][c]*aff[p][k], scatter-fold into sf0
  float a2[4][9];
  {
    int cq = tid & 31;      // c = 4*cq + e
    int pg3 = tid >> 5;     // p = 8*pg3 + pp
    #pragma unroll
    for (int e = 0; e < 4; ++e)
      #pragma unroll
      for (int k = 0; k < 9; ++k) a2[e][k] = 0.f;
    #pragma unroll
    for (int pp = 0; pp < 8; ++pp) {
      int p2 = 8*pg3 + pp;
      float4 pv = *(const float4*)&sp[p2*128 + 4*(cq ^ (p2 & 7))];
      float4 a0 = *(const float4*)&aff_s[p2*12];
      float4 a1 = *(const float4*)&aff_s[p2*12 + 4];
      float a8 = aff_s[p2*12 + 8];
      float av[9] = {a0.x,a0.y,a0.z,a0.w,a1.x,a1.y,a1.z,a1.w,a8};
      #pragma unroll
      for (int k = 0; k < 9; ++k) {
        float a = av[k];
        a2[0][k] += pv.x*a; a2[1][k] += pv.y*a; a2[2][k] += pv.z*a; a2[3][k] += pv.w*a;
      }
    }
    #pragma unroll
    for (int e = 0; e < 4; ++e)
      #pragma unroll
      for (int k = 0; k < 9; ++k)
        a2[e][k] += __shfl_xor(a2[e][k], 32);
  }
  __syncthreads();                 // all done reading sp -> reuse as reduce scratch
  float* red2 = sp;                // 4*32*36 = 4608 floats
  {
    int cq = tid & 31, w = tid >> 6;
    if ((tid & 32) == 0) {
      #pragma unroll
      for (int e = 0; e < 4; ++e)
        #pragma unroll
        for (int k = 0; k < 9; ++k)
          red2[(w*32 + cq)*36 + e*9 + k] = a2[e][k];
    }
  }
  __syncthreads();
  for (int l = tid; l < 1152; l += 256) {
    float v = red2[l] + red2[1152+l] + red2[2304+l] + red2[3456+l];
    int cq = l/36, rem = l - cq*36;
    int e = rem/9, k = rem - e*9;
    int c = 4*cq + e;
    int dh = k/3 - 1, dw = k - (k/3)*3 - 1;
    int hs2 = hs + dh, ws2 = ws + dw;
    if ((unsigned)hs2 < 32u && (unsigned)ws2 < 32u)
      atomicAdd(&sf0[((size_t)b*NTOK + hs2*32 + ws2)*128 + c], v);
  }
}

// ---------------------------------------------------------------------------
// K4: qkv = (sf0 / (affsum+1e-12)) @ qkv_w^T   (M=8192, K=128, N=384)
// ---------------------------------------------------------------------------
__global__ __launch_bounds__(256) void k4_qkv(
    const float* __restrict__ sf0, const float* __restrict__ affsum,
    const float* __restrict__ qw, float* __restrict__ qkv)
{
  __shared__ __align__(16) float As[64*132];
  __shared__ float Bs[64*129];
  __shared__ float rs_s[64];
  int m0 = blockIdx.x*64, j0 = blockIdx.y*64;
  int tid = threadIdx.x;
  if (tid < 64) rs_s[tid] = 1.f / (affsum[m0 + tid] + 1e-12f);
  __syncthreads();
  for (int l = tid; l < 2048; l += 256) {
    int m = l >> 5, kq = l & 31;
    float4 v = *(const float4*)&sf0[(size_t)(m0+m)*128 + 4*kq];
    float rd = rs_s[m];
    v.x*=rd; v.y*=rd; v.z*=rd; v.w*=rd;
    *(float4*)&As[m*132 + 4*kq] = v;
  }
  for (int l = tid; l < 2048; l += 256) {
    int j = l >> 5, kq = l & 31;
    float4 v = *(const float4*)&qw[(size_t)(j0+j)*128 + 4*kq];
    Bs[j*129 + 4*kq+0]=v.x; Bs[j*129 + 4*kq+1]=v.y; Bs[j*129 + 4*kq+2]=v.z; Bs[j*129 + 4*kq+3]=v.w;
  }
  __syncthreads();
  int tj = tid & 15, tm = tid >> 4;
  float acc[4][4];
  #pragma unroll
  for (int r = 0; r < 4; ++r)
    #pragma unroll
    for (int s = 0; s < 4; ++s) acc[r][s] = 0.f;
  for (int kk = 0; kk < 128; ++kk) {
    float a0 = As[(4*tm+0)*132+kk], a1 = As[(4*tm+1)*132+kk], a2v = As[(4*tm+2)*132+kk], a3 = As[(4*tm+3)*132+kk];
    float b0 = Bs[(4*tj+0)*129+kk], b1 = Bs[(4*tj+1)*129+kk], b2 = Bs[(4*tj+2)*129+kk], b3 = Bs[(4*tj+3)*129+kk];
    acc[0][0]+=a0*b0; acc[0][1]+=a0*b1; acc[0][2]+=a0*b2; acc[0][3]+=a0*b3;
    acc[1][0]+=a1*b0; acc[1][1]+=a1*b1; acc[1][2]+=a1*b2; acc[1][3]+=a1*b3;
    acc[2][0]+=a2v*b0; acc[2][1]+=a2v*b1; acc[2][2]+=a2v*b2; acc[2][3]+=a2v*b3;
    acc[3][0]+=a3*b0; acc[3][1]+=a3*b1; acc[3][2]+=a3*b2; acc[3][3]+=a3*b3;
  }
  #pragma unroll
  for (int r = 0; r < 4; ++r) {
    float4 v; v.x=acc[r][0]; v.y=acc[r][1]; v.z=acc[r][2]; v.w=acc[r][3];
    *(float4*)&qkv[(size_t)(m0 + 4*tm + r)*384 + j0 + 4*tj] = v;
  }
}

// ---------------------------------------------------------------------------
// K5: attention over 1024 tokens per (b,h); thread-per-q-row, online softmax
// ---------------------------------------------------------------------------
__global__ __launch_bounds__(128) void k5_attn(const float* __restrict__ qkv, float* __restrict__ o2)
{
  int wg = swz8(blockIdx.x, 64);
  int bh = wg >> 3, qt = wg & 7;
  int b = bh >> 3, h = bh & 7;
  int tid = threadIdx.x;
  size_t tok = (size_t)b*NTOK + qt*128 + tid;
  const float* qp = qkv + tok*384 + h*16;
  float q[16];
  #pragma unroll
  for (int e = 0; e < 4; ++e) {
    float4 v = *(const float4*)&qp[4*e];
    q[4*e]=v.x; q[4*e+1]=v.y; q[4*e+2]=v.z; q[4*e+3]=v.w;
  }
  const float* kb = qkv + (size_t)b*NTOK*384 + 128 + h*16;
  const float* vb = kb + 128;
  float m = -1e30f, l = 0.f, o[16];
  #pragma unroll
  for (int e = 0; e < 16; ++e) o[e] = 0.f;
  for (int ch = 0; ch < 64; ++ch) {
    float s[16];
    #pragma unroll
    for (int jj = 0; jj < 16; ++jj) {
      const float* kr = kb + (size_t)(ch*16 + jj)*384;
      float d = 0.f;
      #pragma unroll
      for (int e = 0; e < 4; ++e) {
        float4 kv = *(const float4*)&kr[4*e];
        d += q[4*e]*kv.x + q[4*e+1]*kv.y + q[4*e+2]*kv.z + q[4*e+3]*kv.w;
      }
      s[jj] = d * SCALE_AT;
    }
    float cm = s[0];
    #pragma unroll
    for (int jj = 1; jj < 16; ++jj) cm = fmaxf(cm, s[jj]);
    float mn = fmaxf(m, cm);
    float corr = __expf(m - mn);
    l *= corr;
    #pragma unroll
    for (int e = 0; e < 16; ++e) o[e] *= corr;
    #pragma unroll
    for (int jj = 0; jj < 16; ++jj) {
      float e1 = __expf(s[jj] - mn);
      l += e1;
      const float* vr = vb + (size_t)(ch*16 + jj)*384;
      #pragma unroll
      for (int e = 0; e < 4; ++e) {
        float4 vv = *(const float4*)&vr[4*e];
        o[4*e]+=e1*vv.x; o[4*e+1]+=e1*vv.y; o[4*e+2]+=e1*vv.z; o[4*e+3]+=e1*vv.w;
      }
    }
    m = mn;
  }
  float inv = 1.f / l;
  float* op = o2 + tok*128 + h*16;
  #pragma unroll
  for (int e = 0; e < 4; ++e) {
    float4 v; v.x=o[4*e]*inv; v.y=o[4*e+1]*inv; v.z=o[4*e+2]*inv; v.w=o[4*e+3]*inv;
    *(float4*)&op[4*e] = v;
  }
}

// ---------------------------------------------------------------------------
// K6: sfn = o2 @ proj_w^T + proj_b  (M=8192, K=128, N=128)
// ---------------------------------------------------------------------------
__global__ __launch_bounds__(256) void k6_proj(
    const float* __restrict__ o2, const float* __restrict__ pw,
    const float* __restrict__ pb, float* __restrict__ sfn)
{
  __shared__ __align__(16) float As[64*132];
  __shared__ float Bs[64*129];
  int m0 = blockIdx.x*64, j0 = blockIdx.y*64;
  int tid = threadIdx.x;
  for (int l = tid; l < 2048; l += 256) {
    int m = l >> 5, kq = l & 31;
    float4 v = *(const float4*)&o2[(size_t)(m0+m)*128 + 4*kq];
    *(float4*)&As[m*132 + 4*kq] = v;
  }
  for (int l = tid; l < 2048; l += 256) {
    int j = l >> 5, kq = l & 31;
    float4 v = *(const float4*)&pw[(size_t)(j0+j)*128 + 4*kq];
    Bs[j*129 + 4*kq+0]=v.x; Bs[j*129 + 4*kq+1]=v.y; Bs[j*129 + 4*kq+2]=v.z; Bs[j*129 + 4*kq+3]=v.w;
  }
  __syncthreads();
  int tj = tid & 15, tm = tid >> 4;
  float acc[4][4];
  #pragma unroll
  for (int r = 0; r < 4; ++r)
    #pragma unroll
    for (int s = 0; s < 4; ++s) acc[r][s] = 0.f;
  for (int kk = 0; kk < 128; ++kk) {
    float a0 = As[(4*tm+0)*132+kk], a1 = As[(4*tm+1)*132+kk], a2v = As[(4*tm+2)*132+kk], a3 = As[(4*tm+3)*132+kk];
    float b0 = Bs[(4*tj+0)*129+kk], b1 = Bs[(4*tj+1)*129+kk], b2 = Bs[(4*tj+2)*129+kk], b3 = Bs[(4*tj+3)*129+kk];
    acc[0][0]+=a0*b0; acc[0][1]+=a0*b1; acc[0][2]+=a0*b2; acc[0][3]+=a0*b3;
    acc[1][0]+=a1*b0; acc[1][1]+=a1*b1; acc[1][2]+=a1*b2; acc[1][3]+=a1*b3;
    acc[2][0]+=a2v*b0; acc[2][1]+=a2v*b1; acc[2][2]+=a2v*b2; acc[2][3]+=a2v*b3;
    acc[3][0]+=a3*b0; acc[3][1]+=a3*b1; acc[3][2]+=a3*b2; acc[3][3]+=a3*b3;
  }
  float bx = pb[j0+4*tj+0], by = pb[j0+4*tj+1], bz = pb[j0+4*tj+2], bw = pb[j0+4*tj+3];
  #pragma unroll
  for (int r = 0; r < 4; ++r) {
    float4 v; v.x=acc[r][0]+bx; v.y=acc[r][1]+by; v.z=acc[r][2]+bz; v.w=acc[r][3]+bw;
    *(float4*)&sfn[(size_t)(m0 + 4*tm + r)*128 + j0 + 4*tj] = v;
  }
}

// ---------------------------------------------------------------------------
// K7: out[c][p] = sum_k st2[k][c] * aff[p][k]  per token, write (B,C,H,W)
// ---------------------------------------------------------------------------
__global__ __launch_bounds__(256) void k7_out(
    const float* __restrict__ sfn, const float* __restrict__ aff_g, float* __restrict__ out)
{
  __shared__ __align__(16) float st2[9*128];
  __shared__ __align__(16) float aff_s[64*12];
  int wg = swz8(blockIdx.x, 1024);
  int b = wg >> 10, n = wg & 1023, hs = n >> 5, ws = n & 31;
  int tid = threadIdx.x;
  for (int l = tid; l < 1152; l += 256) {
    int k = l >> 7, c = l & 127;
    int dh = k/3 - 1, dw = k - (k/3)*3 - 1;
    int hs2 = hs + dh, ws2 = ws + dw;
    float v = 0.f;
    if ((unsigned)hs2 < 32u && (unsigned)ws2 < 32u)
      v = sfn[((size_t)b*NTOK + hs2*32 + ws2)*128 + c];
    st2[l] = v;
  }
  for (int l = tid; l < 576; l += 256) {
    int p = l/9, k = l - p*9;
    aff_s[p*12 + k] = aff_g[(size_t)wg*576 + l];
  }
  __syncthreads();
  int cq = tid & 31;   // c = 4*cq + e
  int pg = tid >> 5;   // p = 8*pg + pp  (one output row i = pg)
  float sr[9][4];
  #pragma unroll
  for (int k = 0; k < 9; ++k) {
    float4 v = *(const float4*)&st2[k*128 + 4*cq];
    sr[k][0]=v.x; sr[k][1]=v.y; sr[k][2]=v.z; sr[k][3]=v.w;
  }
  float ob[4][8];
  #pragma unroll
  for (int pp = 0; pp < 8; ++pp) {
    int p = 8*pg + pp;
    float4 a0 = *(const float4*)&aff_s[p*12];
    float4 a1 = *(const float4*)&aff_s[p*12 + 4];
    float a8 = aff_s[p*12 + 8];
    float av[9] = {a0.x,a0.y,a0.z,a0.w,a1.x,a1.y,a1.z,a1.w,a8};
    #pragma unroll
    for (int e = 0; e < 4; ++e) {
      float acc = 0.f;
      #pragma unroll
      for (int k = 0; k < 9; ++k) acc += sr[k][e]*av[k];
      ob[e][pp] = acc;
    }
  }
  #pragma unroll
  for (int e = 0; e < 4; ++e) {
    int c = 4*cq + e;
    float* dst = out + (((size_t)b*C_ + c)*H_ + (hs*8 + pg))*W_ + ws*8;
    float4 v0; v0.x=ob[e][0]; v0.y=ob[e][1]; v0.z=ob[e][2]; v0.w=ob[e][3];
    float4 v1; v1.x=ob[e][4]; v1.y=ob[e][5]; v1.z=ob[e][6]; v1.w=ob[e][7];
    *(float4*)&dst[0] = v0;
    *(float4*)&dst[4] = v1;
  }
}

// ---------------------------------------------------------------------------
extern "C" void kernel_launch(void* const* d_in, const int* in_sizes, int n_in,
                              void* d_out, int out_size, void* d_ws, size_t ws_size,
                              hipStream_t stream) {
  const float* x    = (const float*)d_in[0];
  const float* lnw  = (const float*)d_in[1];
  const float* lnb  = (const float*)d_in[2];
  const float* qkvw = (const float*)d_in[3];
  const float* projw= (const float*)d_in[4];
  const float* projb= (const float*)d_in[5];
  float* out = (float*)d_out;

  float* ws   = (float*)d_ws;
  float* stok = ws;                    // 1,048,576
  float* gmu  = stok + 1048576;        //   524,288
  float* grs  = gmu  + 524288;         //   524,288
  float* aff  = grs  + 524288;         // 4,718,592
  float* afs  = aff  + 4718592;        //     8,192
  float* sf0  = afs  + 8192;           // 1,048,576
  float* qkv  = sf0  + 1048576;        // 3,145,728
  float* o2   = qkv  + 3145728;        // 1,048,576
  float* sfn  = o2   + 1048576;        // 1,048,576  (total ~52.5 MB)

  hipMemsetAsync(sf0, 0, (size_t)1048576*4, stream);
  hipMemsetAsync(afs, 0, (size_t)8192*4, stream);

  k1_ln_stoken<<<dim3(8192), dim3(256), 0, stream>>>(x, lnw, lnb, stok, gmu, grs);
  k2_aff<<<dim3(8192), dim3(256), 0, stream>>>(x, lnw, lnb, stok, gmu, grs, aff, afs, sf0);
  k4_qkv<<<dim3(128, 6), dim3(256), 0, stream>>>(sf0, afs, qkvw, qkv);
  k5_attn<<<dim3(512), dim3(128), 0, stream>>>(qkv, o2);
  k6_proj<<<dim3(128, 2), dim3(256), 0, stream>>>(o2, projw, projb, sfn);
  k7_out<<<dim3(8192), dim3(256), 0, stream>>>(sfn, aff, out);
}

// Round 2
// 975.122 us; speedup vs baseline: 1.2427x; 1.2427x over previous
//
#include <hip/hip_runtime.h>
#include <cstdint>
#include <cstddef>

// Problem constants (fixed shapes from reference)
#define B_    8
#define C_    128
#define H_    256
#define W_    256
#define HWSZ  (256*256)
#define HS_   32
#define WS_   32
#define NTOK  1024          // tokens per batch (Hs*Ws)
#define PP_   64            // pixels per patch
#define EPS_  1e-6f
#define SCALE_QK 0.08838834764831845f   // 128^-0.5
#define SCALE_AT 0.25f                  // 16^-0.5

// bijective XCD swizzle: nwg divisible by 8; chunk = nwg/8
__device__ __forceinline__ int swz8(int wg, int chunk) {
  return (wg & 7) * chunk + (wg >> 3);
}

// ---------------------------------------------------------------------------
// K1: per-pixel LayerNorm stats (mu, rstd) + stoken = 8x8 block mean of LN(x)
// one block per patch; LDS pix layout [p][c] with c-block XOR swizzle
// ---------------------------------------------------------------------------
__global__ __launch_bounds__(256) void k1_ln_stoken(
    const float* __restrict__ x, const float* __restrict__ lnw, const float* __restrict__ lnb,
    float* __restrict__ stok, float* __restrict__ gmu, float* __restrict__ grs)
{
  __shared__ __align__(16) float sp[64*128];
  __shared__ float reds[4*64], redq[4*64];
  __shared__ float smu[64], srs[64];
  int wg = swz8(blockIdx.x, 1024);
  int b = wg >> 10, n = wg & 1023;
  int hs = n >> 5, ws = n & 31;
  int tid = threadIdx.x;

  int p = tid & 63;
  int pi = p >> 3, pj = p & 7;
  const float* xpix = x + (size_t)b*C_*HWSZ + (size_t)(hs*8 + pi)*W_ + (ws*8 + pj);
  #pragma unroll
  for (int it = 0; it < 8; ++it) {
    int cb = it*4 + (tid >> 6);       // c-block of 4
    int c0 = cb*4;
    float v0 = xpix[(size_t)(c0+0)*HWSZ];
    float v1 = xpix[(size_t)(c0+1)*HWSZ];
    float v2 = xpix[(size_t)(c0+2)*HWSZ];
    float v3 = xpix[(size_t)(c0+3)*HWSZ];
    float4 v; v.x=v0; v.y=v1; v.z=v2; v.w=v3;
    *(float4*)&sp[p*128 + 4*(cb ^ (p & 7))] = v;
  }
  __syncthreads();
  // per-pixel stats over C
  {
    int pp2 = tid & 63, cq = tid >> 6;
    float s = 0.f, q = 0.f;
    #pragma unroll
    for (int e = 0; e < 8; ++e) {
      int cb = cq*8 + e;
      float4 v = *(const float4*)&sp[pp2*128 + 4*(cb ^ (pp2 & 7))];
      s += v.x + v.y + v.z + v.w;
      q += v.x*v.x + v.y*v.y + v.z*v.z + v.w*v.w;
    }
    reds[cq*64 + pp2] = s; redq[cq*64 + pp2] = q;
  }
  __syncthreads();
  if (tid < 64) {
    float s = reds[tid] + reds[64+tid] + reds[128+tid] + reds[192+tid];
    float q = redq[tid] + redq[64+tid] + redq[128+tid] + redq[192+tid];
    float mu = s * (1.f/128.f);
    float var = q * (1.f/128.f) - mu*mu;
    float rs = rsqrtf(var + EPS_);
    smu[tid] = mu; srs[tid] = rs;
    size_t base = (size_t)wg*64 + tid;
    gmu[base] = mu; grs[base] = rs;
  }
  __syncthreads();
  // stoken: per-c mean over 64 pixels of normalized values
  {
    int c = tid >> 1, ph = tid & 1;
    float s = 0.f;
    #pragma unroll
    for (int q = 0; q < 32; ++q) {
      int pr = ph*32 + q;
      float v = sp[pr*128 + 4*((c >> 2) ^ (pr & 7)) + (c & 3)];
      s += (v - smu[pr]) * srs[pr];
    }
    s += __shfl_xor(s, 1);
    if (ph == 0)
      stok[(size_t)wg*128 + c] = lnw[c] * (s * (1.f/64.f)) + lnb[c];
  }
}

// ---------------------------------------------------------------------------
// K2: per-token: aff = softmax(pix @ st * scale), scatter-fold pix^T@aff -> sf0
//     (atomics), scatter-fold sum_p(aff) -> affsum, write aff
// ---------------------------------------------------------------------------
__global__ __launch_bounds__(256) void k2_aff(
    const float* __restrict__ x, const float* __restrict__ lnw, const float* __restrict__ lnb,
    const float* __restrict__ stok, const float* __restrict__ gmu, const float* __restrict__ grs,
    float* __restrict__ aff_g, float* __restrict__ affsum, float* __restrict__ sf0)
{
  __shared__ __align__(16) float sp[64*128];      // normalized pix [p][c swizzled]
  __shared__ __align__(16) float st_s[9*128];     // [k][c]
  __shared__ __align__(16) float aff_s[64*12];    // [p][k] padded to 12
  __shared__ float smu[64], srs[64], wl[128], bl[128];
  __shared__ float red[4*16*36];                  // phase2 cross-wave reduce
  int wg = swz8(blockIdx.x, 1024);
  int b = wg >> 10, n = wg & 1023, hs = n >> 5, ws = n & 31;
  int tid = threadIdx.x;

  // phase 0: small loads
  if (tid < 64) { smu[tid] = gmu[(size_t)wg*64 + tid]; srs[tid] = grs[(size_t)wg*64 + tid]; }
  else if (tid < 192) { int l = tid - 64; wl[l] = lnw[l]; bl[l] = lnb[l]; }
  for (int l = tid; l < 1152; l += 256) {
    int k = l >> 7, c = l & 127;
    int dh = k/3 - 1, dw = k - (k/3)*3 - 1;
    int hs2 = hs + dh, ws2 = ws + dw;
    float v = 0.f;
    if ((unsigned)hs2 < 32u && (unsigned)ws2 < 32u)
      v = stok[((size_t)b*NTOK + hs2*32 + ws2)*128 + c];
    st_s[l] = v;
  }
  __syncthreads();
  // phase 1: load x patch, normalize, store swizzled
  {
    int p = tid & 63;
    int pi = p >> 3, pj = p & 7;
    const float* xpix = x + (size_t)b*C_*HWSZ + (size_t)(hs*8 + pi)*W_ + (ws*8 + pj);
    float mu = smu[p], rs = srs[p];
    #pragma unroll
    for (int it = 0; it < 8; ++it) {
      int cb = it*4 + (tid >> 6);
      int c0 = cb*4;
      float v0 = xpix[(size_t)(c0+0)*HWSZ];
      float v1 = xpix[(size_t)(c0+1)*HWSZ];
      float v2 = xpix[(size_t)(c0+2)*HWSZ];
      float v3 = xpix[(size_t)(c0+3)*HWSZ];
      float4 y;
      y.x = wl[c0+0]*((v0-mu)*rs) + bl[c0+0];
      y.y = wl[c0+1]*((v1-mu)*rs) + bl[c0+1];
      y.z = wl[c0+2]*((v2-mu)*rs) + bl[c0+2];
      y.w = wl[c0+3]*((v3-mu)*rs) + bl[c0+3];
      *(float4*)&sp[p*128 + 4*(cb ^ (p & 7))] = y;
    }
  }
  __syncthreads();
  // phase 2: logits[p][k] = sum_c pix[p][c]*st[k][c]
  {
    int pg = tid & 15;      // p = 4*pg + r
    int cg = tid >> 4;      // c = 8*cg .. 8*cg+7
    float pr[4][8];
    #pragma unroll
    for (int r = 0; r < 4; ++r) {
      int p2 = 4*pg + r;
      #pragma unroll
      for (int hh = 0; hh < 2; ++hh) {
        int cb = 2*cg + hh;
        float4 v = *(const float4*)&sp[p2*128 + 4*(cb ^ (p2 & 7))];
        pr[r][hh*4+0]=v.x; pr[r][hh*4+1]=v.y; pr[r][hh*4+2]=v.z; pr[r][hh*4+3]=v.w;
      }
    }
    float acc[4][9];
    #pragma unroll
    for (int r = 0; r < 4; ++r)
      #pragma unroll
      for (int k = 0; k < 9; ++k) acc[r][k] = 0.f;
    #pragma unroll
    for (int k = 0; k < 9; ++k) {
      float4 s0 = *(const float4*)&st_s[k*128 + 8*cg];
      float4 s1 = *(const float4*)&st_s[k*128 + 8*cg + 4];
      #pragma unroll
      for (int r = 0; r < 4; ++r)
        acc[r][k] += pr[r][0]*s0.x + pr[r][1]*s0.y + pr[r][2]*s0.z + pr[r][3]*s0.w
                   + pr[r][4]*s1.x + pr[r][5]*s1.y + pr[r][6]*s1.z + pr[r][7]*s1.w;
    }
    #pragma unroll
    for (int r = 0; r < 4; ++r)
      #pragma unroll
      for (int k = 0; k < 9; ++k) {
        float v = acc[r][k];
        v += __shfl_xor(v, 16);
        v += __shfl_xor(v, 32);
        acc[r][k] = v;
      }
    if ((tid & 48) == 0) {
      int w = tid >> 6;
      #pragma unroll
      for (int r = 0; r < 4; ++r)
        #pragma unroll
        for (int k = 0; k < 9; ++k)
          red[(w*16 + pg)*36 + r*9 + k] = acc[r][k];
    }
  }
  __syncthreads();
  for (int l = tid; l < 576; l += 256) {
    float v = red[l] + red[576+l] + red[1152+l] + red[1728+l];
    int pg = l/36, rem = l - pg*36;
    int r = rem/9, k = rem - r*9;
    aff_s[(4*pg + r)*12 + k] = v * SCALE_QK;
  }
  __syncthreads();
  if (tid < 64) {  // softmax over 9
    float mx = -1e30f;
    #pragma unroll
    for (int k = 0; k < 9; ++k) mx = fmaxf(mx, aff_s[tid*12 + k]);
    float e[9]; float ssum = 0.f;
    #pragma unroll
    for (int k = 0; k < 9; ++k) { e[k] = __expf(aff_s[tid*12 + k] - mx); ssum += e[k]; }
    float inv = 1.f / ssum;
    #pragma unroll
    for (int k = 0; k < 9; ++k) aff_s[tid*12 + k] = e[k]*inv;
  }
  __syncthreads();
  // write aff + affsum scatter
  for (int l = tid; l < 576; l += 256) {
    int p2 = l/9, k = l - p2*9;
    aff_g[(size_t)wg*576 + l] = aff_s[p2*12 + k];
  }
  if (tid < 9) {
    int k = tid;
    float s = 0.f;
    for (int p2 = 0; p2 < 64; ++p2) s += aff_s[p2*12 + k];
    int dh = k/3 - 1, dw = k - (k/3)*3 - 1;
    int hs2 = hs + dh, ws2 = ws + dw;
    if ((unsigned)hs2 < 32u && (unsigned)ws2 < 32u)
      atomicAdd(&affsum[(size_t)b*NTOK + hs2*32 + ws2], s);
  }
  // phase 3: sfpre[c][k] = sum_p pix[p][c]*aff[p][k], scatter-fold into sf0
  float a2[4][9];
  {
    int cq = tid & 31;      // c = 4*cq + e
    int pg3 = tid >> 5;     // p = 8*pg3 + pp
    #pragma unroll
    for (int e = 0; e < 4; ++e)
      #pragma unroll
      for (int k = 0; k < 9; ++k) a2[e][k] = 0.f;
    #pragma unroll
    for (int pp = 0; pp < 8; ++pp) {
      int p2 = 8*pg3 + pp;
      float4 pv = *(const float4*)&sp[p2*128 + 4*(cq ^ (p2 & 7))];
      float4 a0 = *(const float4*)&aff_s[p2*12];
      float4 a1 = *(const float4*)&aff_s[p2*12 + 4];
      float a8 = aff_s[p2*12 + 8];
      float av[9] = {a0.x,a0.y,a0.z,a0.w,a1.x,a1.y,a1.z,a1.w,a8};
      #pragma unroll
      for (int k = 0; k < 9; ++k) {
        float a = av[k];
        a2[0][k] += pv.x*a; a2[1][k] += pv.y*a; a2[2][k] += pv.z*a; a2[3][k] += pv.w*a;
      }
    }
    #pragma unroll
    for (int e = 0; e < 4; ++e)
      #pragma unroll
      for (int k = 0; k < 9; ++k)
        a2[e][k] += __shfl_xor(a2[e][k], 32);
  }
  __syncthreads();                 // all done reading sp -> reuse as reduce scratch
  float* red2 = sp;                // 4*32*36 = 4608 floats
  {
    int cq = tid & 31, w = tid >> 6;
    if ((tid & 32) == 0) {
      #pragma unroll
      for (int e = 0; e < 4; ++e)
        #pragma unroll
        for (int k = 0; k < 9; ++k)
          red2[(w*32 + cq)*36 + e*9 + k] = a2[e][k];
    }
  }
  __syncthreads();
  for (int l = tid; l < 1152; l += 256) {
    float v = red2[l] + red2[1152+l] + red2[2304+l] + red2[3456+l];
    int cq = l/36, rem = l - cq*36;
    int e = rem/9, k = rem - e*9;
    int c = 4*cq + e;
    int dh = k/3 - 1, dw = k - (k/3)*3 - 1;
    int hs2 = hs + dh, ws2 = ws + dw;
    if ((unsigned)hs2 < 32u && (unsigned)ws2 < 32u)
      atomicAdd(&sf0[((size_t)b*NTOK + hs2*32 + ws2)*128 + c], v);
  }
}

// ---------------------------------------------------------------------------
// K4: qkv = (sf0 / (affsum+1e-12)) @ qkv_w^T   (M=8192, K=128, N=384)
// kk-step-4, ds_read_b128, per-row XOR col swizzle c=(row>>2)&7:
//   A reads: 4 distinct addrs (broadcast16), 4 distinct banks -> free
//   B reads: 16 rows spread over 8 banks, 2-way -> free
// ---------------------------------------------------------------------------
__global__ __launch_bounds__(256) void k4_qkv(
    const float* __restrict__ sf0, const float* __restrict__ affsum,
    const float* __restrict__ qw, float* __restrict__ qkv)
{
  __shared__ __align__(16) float As[64*128];
  __shared__ __align__(16) float Bs[64*128];
  __shared__ float rs_s[64];
  int m0 = blockIdx.x*64, j0 = blockIdx.y*64;
  int tid = threadIdx.x;
  if (tid < 64) rs_s[tid] = 1.f / (affsum[m0 + tid] + 1e-12f);
  __syncthreads();
  for (int l = tid; l < 2048; l += 256) {
    int m = l >> 5, kq = l & 31;
    float4 v = *(const float4*)&sf0[(size_t)(m0+m)*128 + 4*kq];
    float rd = rs_s[m];
    v.x*=rd; v.y*=rd; v.z*=rd; v.w*=rd;
    *(float4*)&As[m*128 + 4*(kq ^ ((m>>2) & 7))] = v;
  }
  for (int l = tid; l < 2048; l += 256) {
    int j = l >> 5, kq = l & 31;
    float4 v = *(const float4*)&qw[(size_t)(j0+j)*128 + 4*kq];
    *(float4*)&Bs[j*128 + 4*(kq ^ ((j>>2) & 7))] = v;
  }
  __syncthreads();
  int tj = tid & 15, tm = tid >> 4;
  float acc[4][4];
  #pragma unroll
  for (int r = 0; r < 4; ++r)
    #pragma unroll
    for (int s = 0; s < 4; ++s) acc[r][s] = 0.f;
  for (int kq = 0; kq < 32; ++kq) {
    float4 a[4], bq[4];
    #pragma unroll
    for (int r = 0; r < 4; ++r)
      a[r] = *(const float4*)&As[(4*tm+r)*128 + 4*(kq ^ (tm & 7))];
    #pragma unroll
    for (int s = 0; s < 4; ++s)
      bq[s] = *(const float4*)&Bs[(4*tj+s)*128 + 4*(kq ^ (tj & 7))];
    #pragma unroll
    for (int r = 0; r < 4; ++r)
      #pragma unroll
      for (int s = 0; s < 4; ++s)
        acc[r][s] += a[r].x*bq[s].x + a[r].y*bq[s].y + a[r].z*bq[s].z + a[r].w*bq[s].w;
  }
  #pragma unroll
  for (int r = 0; r < 4; ++r) {
    float4 v; v.x=acc[r][0]; v.y=acc[r][1]; v.z=acc[r][2]; v.w=acc[r][3];
    *(float4*)&qkv[(size_t)(m0 + 4*tm + r)*384 + j0 + 4*tj] = v;
  }
}

// ---------------------------------------------------------------------------
// K5: attention over 1024 tokens per (b,h); 8-way KV lane-split, no LDS,
// shfl-based exact online-softmax combine. 2048 blocks x 256 thr = 32 w/CU.
// wave layout: lane = sp*8 + ql; ql = q-row-in-wave, sp = KV slice
// ---------------------------------------------------------------------------
__global__ __launch_bounds__(256) void k5_attn(const float* __restrict__ qkv, float* __restrict__ o2)
{
  int wg = swz8(blockIdx.x, 256);   // 2048 blocks
  int bh = wg >> 5;                  // 0..63
  int tt = wg & 31;                  // token tile (32 tokens)
  int b = bh >> 3, h = bh & 7;
  int tid = threadIdx.x;
  int wave = tid >> 6, lane = tid & 63;
  int ql = lane & 7, sp = lane >> 3;
  int t = tt*32 + wave*8 + ql;       // token in [0,1024)

  const float* qp = qkv + ((size_t)b*NTOK + t)*384 + h*16;
  float q[16];
  #pragma unroll
  for (int e = 0; e < 4; ++e) {
    float4 v = *(const float4*)&qp[4*e];
    q[4*e]=v.x; q[4*e+1]=v.y; q[4*e+2]=v.z; q[4*e+3]=v.w;
  }
  const float* kb = qkv + (size_t)b*NTOK*384 + 128 + h*16;
  const float* vb = kb + 128;
  float m = -1e30f, l = 0.f, o[16];
  #pragma unroll
  for (int e = 0; e < 16; ++e) o[e] = 0.f;

  // this thread's KV set: kv = 8*i + sp, i in [0,128); chunks of 8
  for (int c = 0; c < 16; ++c) {
    float s[8];
    #pragma unroll
    for (int j = 0; j < 8; ++j) {
      int kv = (c*8 + j)*8 + sp;
      const float* kr = kb + (size_t)kv*384;
      float d = 0.f;
      #pragma unroll
      for (int e = 0; e < 4; ++e) {
        float4 kvv = *(const float4*)&kr[4*e];
        d += q[4*e]*kvv.x + q[4*e+1]*kvv.y + q[4*e+2]*kvv.z + q[4*e+3]*kvv.w;
      }
      s[j] = d * SCALE_AT;
    }
    float cm = s[0];
    #pragma unroll
    for (int j = 1; j < 8; ++j) cm = fmaxf(cm, s[j]);
    float mn = fmaxf(m, cm);
    float corr = __expf(m - mn);
    l *= corr;
    #pragma unroll
    for (int e = 0; e < 16; ++e) o[e] *= corr;
    #pragma unroll
    for (int j = 0; j < 8; ++j) {
      float e1 = __expf(s[j] - mn);
      l += e1;
      int kv = (c*8 + j)*8 + sp;
      const float* vr = vb + (size_t)kv*384;
      #pragma unroll
      for (int e = 0; e < 4; ++e) {
        float4 vv = *(const float4*)&vr[4*e];
        o[4*e]   += e1*vv.x; o[4*e+1] += e1*vv.y;
        o[4*e+2] += e1*vv.z; o[4*e+3] += e1*vv.w;
      }
    }
    m = mn;
  }

  // exact online-softmax combine across the 8 sp slices (lane bits 3..5)
  #pragma unroll
  for (int d = 8; d <= 32; d <<= 1) {
    float mo = __shfl_xor(m, d);
    float lo = __shfl_xor(l, d);
    float M  = fmaxf(m, mo);
    float ca = __expf(m - M), cb = __expf(mo - M);
    #pragma unroll
    for (int e = 0; e < 16; ++e) {
      float oo = __shfl_xor(o[e], d);
      o[e] = o[e]*ca + oo*cb;
    }
    l = l*ca + lo*cb;
    m = M;
  }
  if (sp == 0) {
    float inv = 1.f / l;
    float* op = o2 + ((size_t)b*NTOK + t)*128 + h*16;
    #pragma unroll
    for (int e = 0; e < 4; ++e) {
      float4 v; v.x=o[4*e]*inv; v.y=o[4*e+1]*inv; v.z=o[4*e+2]*inv; v.w=o[4*e+3]*inv;
      *(float4*)&op[4*e] = v;
    }
  }
}

// ---------------------------------------------------------------------------
// K6: sfn = o2 @ proj_w^T + proj_b  (M=8192, K=128, N=128) — same scheme as K4
// ---------------------------------------------------------------------------
__global__ __launch_bounds__(256) void k6_proj(
    const float* __restrict__ o2, const float* __restrict__ pw,
    const float* __restrict__ pb, float* __restrict__ sfn)
{
  __shared__ __align__(16) float As[64*128];
  __shared__ __align__(16) float Bs[64*128];
  int m0 = blockIdx.x*64, j0 = blockIdx.y*64;
  int tid = threadIdx.x;
  for (int l = tid; l < 2048; l += 256) {
    int m = l >> 5, kq = l & 31;
    float4 v = *(const float4*)&o2[(size_t)(m0+m)*128 + 4*kq];
    *(float4*)&As[m*128 + 4*(kq ^ ((m>>2) & 7))] = v;
  }
  for (int l = tid; l < 2048; l += 256) {
    int j = l >> 5, kq = l & 31;
    float4 v = *(const float4*)&pw[(size_t)(j0+j)*128 + 4*kq];
    *(float4*)&Bs[j*128 + 4*(kq ^ ((j>>2) & 7))] = v;
  }
  __syncthreads();
  int tj = tid & 15, tm = tid >> 4;
  float acc[4][4];
  #pragma unroll
  for (int r = 0; r < 4; ++r)
    #pragma unroll
    for (int s = 0; s < 4; ++s) acc[r][s] = 0.f;
  for (int kq = 0; kq < 32; ++kq) {
    float4 a[4], bq[4];
    #pragma unroll
    for (int r = 0; r < 4; ++r)
      a[r] = *(const float4*)&As[(4*tm+r)*128 + 4*(kq ^ (tm & 7))];
    #pragma unroll
    for (int s = 0; s < 4; ++s)
      bq[s] = *(const float4*)&Bs[(4*tj+s)*128 + 4*(kq ^ (tj & 7))];
    #pragma unroll
    for (int r = 0; r < 4; ++r)
      #pragma unroll
      for (int s = 0; s < 4; ++s)
        acc[r][s] += a[r].x*bq[s].x + a[r].y*bq[s].y + a[r].z*bq[s].z + a[r].w*bq[s].w;
  }
  float bx = pb[j0+4*tj+0], by = pb[j0+4*tj+1], bz = pb[j0+4*tj+2], bw = pb[j0+4*tj+3];
  #pragma unroll
  for (int r = 0; r < 4; ++r) {
    float4 v; v.x=acc[r][0]+bx; v.y=acc[r][1]+by; v.z=acc[r][2]+bz; v.w=acc[r][3]+bw;
    *(float4*)&sfn[(size_t)(m0 + 4*tm + r)*128 + j0 + 4*tj] = v;
  }
}

// ---------------------------------------------------------------------------
// K7: out[c][p] = sum_k st2[k][c] * aff[p][k]  per token, write (B,C,H,W)
// ---------------------------------------------------------------------------
__global__ __launch_bounds__(256) void k7_out(
    const float* __restrict__ sfn, const float* __restrict__ aff_g, float* __restrict__ out)
{
  __shared__ __align__(16) float st2[9*128];
  __shared__ __align__(16) float aff_s[64*12];
  int wg = swz8(blockIdx.x, 1024);
  int b = wg >> 10, n = wg & 1023, hs = n >> 5, ws = n & 31;
  int tid = threadIdx.x;
  for (int l = tid; l < 1152; l += 256) {
    int k = l >> 7, c = l & 127;
    int dh = k/3 - 1, dw = k - (k/3)*3 - 1;
    int hs2 = hs + dh, ws2 = ws + dw;
    float v = 0.f;
    if ((unsigned)hs2 < 32u && (unsigned)ws2 < 32u)
      v = sfn[((size_t)b*NTOK + hs2*32 + ws2)*128 + c];
    st2[l] = v;
  }
  for (int l = tid; l < 576; l += 256) {
    int p = l/9, k = l - p*9;
    aff_s[p*12 + k] = aff_g[(size_t)wg*576 + l];
  }
  __syncthreads();
  int cq = tid & 31;   // c = 4*cq + e
  int pg = tid >> 5;   // p = 8*pg + pp  (one output row i = pg)
  float sr[9][4];
  #pragma unroll
  for (int k = 0; k < 9; ++k) {
    float4 v = *(const float4*)&st2[k*128 + 4*cq];
    sr[k][0]=v.x; sr[k][1]=v.y; sr[k][2]=v.z; sr[k][3]=v.w;
  }
  float ob[4][8];
  #pragma unroll
  for (int pp = 0; pp < 8; ++pp) {
    int p = 8*pg + pp;
    float4 a0 = *(const float4*)&aff_s[p*12];
    float4 a1 = *(const float4*)&aff_s[p*12 + 4];
    float a8 = aff_s[p*12 + 8];
    float av[9] = {a0.x,a0.y,a0.z,a0.w,a1.x,a1.y,a1.z,a1.w,a8};
    #pragma unroll
    for (int e = 0; e < 4; ++e) {
      float acc = 0.f;
      #pragma unroll
      for (int k = 0; k < 9; ++k) acc += sr[k][e]*av[k];
      ob[e][pp] = acc;
    }
  }
  #pragma unroll
  for (int e = 0; e < 4; ++e) {
    int c = 4*cq + e;
    float* dst = out + (((size_t)b*C_ + c)*H_ + (hs*8 + pg))*W_ + ws*8;
    float4 v0; v0.x=ob[e][0]; v0.y=ob[e][1]; v0.z=ob[e][2]; v0.w=ob[e][3];
    float4 v1; v1.x=ob[e][4]; v1.y=ob[e][5]; v1.z=ob[e][6]; v1.w=ob[e][7];
    *(float4*)&dst[0] = v0;
    *(float4*)&dst[4] = v1;
  }
}

// ---------------------------------------------------------------------------
extern "C" void kernel_launch(void* const* d_in, const int* in_sizes, int n_in,
                              void* d_out, int out_size, void* d_ws, size_t ws_size,
                              hipStream_t stream) {
  const float* x    = (const float*)d_in[0];
  const float* lnw  = (const float*)d_in[1];
  const float* lnb  = (const float*)d_in[2];
  const float* qkvw = (const float*)d_in[3];
  const float* projw= (const float*)d_in[4];
  const float* projb= (const float*)d_in[5];
  float* out = (float*)d_out;

  float* ws   = (float*)d_ws;
  float* stok = ws;                    // 1,048,576
  float* gmu  = stok + 1048576;        //   524,288
  float* grs  = gmu  + 524288;         //   524,288
  float* aff  = grs  + 524288;         // 4,718,592
  float* afs  = aff  + 4718592;        //     8,192
  float* sf0  = afs  + 8192;           // 1,048,576
  float* qkv  = sf0  + 1048576;        // 3,145,728
  float* o2   = qkv  + 3145728;        // 1,048,576
  float* sfn  = o2   + 1048576;        // 1,048,576  (total ~52.5 MB)

  hipMemsetAsync(sf0, 0, (size_t)1048576*4, stream);
  hipMemsetAsync(afs, 0, (size_t)8192*4, stream);

  k1_ln_stoken<<<dim3(8192), dim3(256), 0, stream>>>(x, lnw, lnb, stok, gmu, grs);
  k2_aff<<<dim3(8192), dim3(256), 0, stream>>>(x, lnw, lnb, stok, gmu, grs, aff, afs, sf0);
  k4_qkv<<<dim3(128, 6), dim3(256), 0, stream>>>(sf0, afs, qkvw, qkv);
  k5_attn<<<dim3(2048), dim3(256), 0, stream>>>(qkv, o2);
  k6_proj<<<dim3(128, 2), dim3(256), 0, stream>>>(o2, projw, projb, sfn);
  k7_out<<<dim3(8192), dim3(256), 0, stream>>>(sfn, aff, out);
}